// Round 8
// baseline (5693.277 us; speedup 1.0000x reference)
//
#include <hip/hip_runtime.h>
#include <hip/hip_cooperative_groups.h>
#include <stdint.h>

#define H      160
#define G3     480
#define NCH    10
#define TCH    20
#define CC     200
#define NCLS   16
#define NLAYERS 160
#define NITER  200     // clock: branches k<20; layer l,t at k=20+l+t (max 188); full GRU k<200

namespace cg = cooperative_groups;
typedef unsigned int u32;

__device__ float g_seq[(NLAYERS + 1) * NCH * H];   // [161][10][160]
__device__ float g_xlb[H];

__device__ __forceinline__ float sigm(float x){ return 1.0f / (1.0f + expf(-x)); }

__device__ __forceinline__ float dot160(const float4* __restrict__ w, const float* v){
  float a0 = 0.f, a1 = 0.f;
#pragma unroll
  for (int q = 0; q < 40; q += 2){
    float4 wa = w[q], wb = w[q+1];
    float4 va = *(const float4*)(v + 4*q);
    float4 vb = *(const float4*)(v + 4*q + 4);
    a0 = fmaf(wa.x, va.x, a0); a0 = fmaf(wa.y, va.y, a0);
    a0 = fmaf(wa.z, va.z, a0); a0 = fmaf(wa.w, va.w, a0);
    a1 = fmaf(wb.x, vb.x, a1); a1 = fmaf(wb.y, vb.y, a1);
    a1 = fmaf(wb.z, vb.z, a1); a1 = fmaf(wb.w, vb.w, a1);
  }
  return a0 + a1;
}

extern "C" __global__ __launch_bounds__(512, 2)
void spectral_coop(
  const float* __restrict__ x,
  const float* __restrict__ b_wih, const float* __restrict__ b_whh,
  const float* __restrict__ b_bih, const float* __restrict__ b_bhh,
  const float* __restrict__ g_wih, const float* __restrict__ g_whh,
  const float* __restrict__ g_bih, const float* __restrict__ g_bhh,
  const float* __restrict__ g3_wih, const float* __restrict__ g3_whh,
  const float* __restrict__ g3_bih, const float* __restrict__ g3_bhh,
  const float* __restrict__ bn_gamma, const float* __restrict__ bn_beta,
  const float* __restrict__ bn_mean,  const float* __restrict__ bn_var,
  const float* __restrict__ fc_w, const float* __restrict__ fc_b,
  const float* __restrict__ reg_w, const float* __restrict__ reg_b,
  float* __restrict__ out)
{
  cg::grid_group grid = cg::this_grid();
  const int tid = threadIdx.x;
  const int bid = blockIdx.x;

  __shared__ __align__(16) float sx[H];
  __shared__ __align__(16) float sh[H];
  __shared__ float spre[2*H];
  __shared__ float sxn[H];
  __shared__ float shn[H];
  __shared__ float sxc[H];

  const bool is_layer  = (bid < NLAYERS);
  const bool is_branch = (bid >= NLAYERS) && (bid < NLAYERS + NCH);
  const int  l = bid;
  const int  b = bid - NLAYERS;

  const float4* wih_row = nullptr;
  float4 whhr[40];
  float wij = 0.f, bihj = 0.f, bhhj = 0.f;

  if (is_layer){
    if (tid < G3){
      wih_row = (const float4*)(g3_wih + ((size_t)l*G3 + tid)*H);
      const float4* ph = (const float4*)(g3_whh + ((size_t)l*G3 + tid)*H);
#pragma unroll
      for (int q = 0; q < 40; q++) whhr[q] = ph[q];
      bihj = g3_bih[l*G3 + tid];
      bhhj = g3_bhh[l*G3 + tid];
    }
  } else if (is_branch){
    if (tid < G3){
      const float4* ph = (const float4*)(b_whh + ((size_t)b*G3 + tid)*H);
#pragma unroll
      for (int q = 0; q < 40; q++) whhr[q] = ph[q];
      wij  = b_wih[b*G3 + tid];
      bihj = b_bih[b*G3 + tid];
      bhhj = b_bhh[b*G3 + tid];
    }
  } else {
    if (tid < G3){
      const float4* ph = (const float4*)(g_whh + (size_t)tid * H);
#pragma unroll
      for (int q = 0; q < 40; q++) whhr[q] = ph[q];
      wij  = g_wih[tid];
      bihj = g_bih[tid];
      bhhj = g_bhh[tid];
    }
  }
  if (tid < H) sh[tid] = 0.f;
  __syncthreads();

  float hsum = 0.f;
  float* seq_in  = g_seq + (size_t)(is_layer ? l     : 0) * NCH * H;
  float* seq_out = g_seq + (size_t)(is_layer ? l + 1 : 0) * NCH * H;

  for (int k = 0; k < NITER; k++){
    if (is_layer){
      const int t = k - 20 - l;
      if (t >= 0 && t < NCH){
        if (tid < H) sx[tid] = seq_in[t*H + tid];
        __syncthreads();
        if (tid < G3){
          float ax = bihj + dot160(wih_row, sx);
          float ah = bhhj + dot160(whhr, sh);
          if (tid < 2*H) spre[tid] = ax + ah;
          else { sxn[tid - 2*H] = ax; shn[tid - 2*H] = ah; }
        }
        __syncthreads();
        if (tid < H){
          float r = sigm(spre[tid]);
          float z = sigm(spre[H + tid]);
          float n = tanhf(sxn[tid] + r * shn[tid]);
          float h = (1.f - z) * n + z * sh[tid];
          sh[tid] = h;
          hsum += h;
          seq_out[t*H + tid] = h;
        }
      }
    } else if (is_branch){
      if (k < TCH){
        const int t = k;
        float xv = x[b*TCH + t];
        if (tid < G3){
          float ax = fmaf(xv, wij, bihj);
          float ah = bhhj + dot160(whhr, sh);
          if (tid < 2*H) spre[tid] = ax + ah;
          else { sxn[tid - 2*H] = ax; shn[tid - 2*H] = ah; }
        }
        __syncthreads();
        if (tid < H){
          float r = sigm(spre[tid]);
          float z = sigm(spre[H + tid]);
          float n = tanhf(sxn[tid] + r * shn[tid]);
          float h = (1.f - z) * n + z * sh[tid];
          sh[tid] = h;
          if (t == TCH - 1) g_seq[(size_t)b*H + tid] = h;   // level 0, position b
        }
        __syncthreads();
      }
    } else {
      const int t = k;
      float xv = x[t];
      if (tid < G3){
        float ax = fmaf(xv, wij, bihj);
        float ah = bhhj + dot160(whhr, sh);
        if (tid < 2*H) spre[tid] = ax + ah;
        else { sxn[tid - 2*H] = ax; shn[tid - 2*H] = ah; }
      }
      __syncthreads();
      if (tid < H){
        float r = sigm(spre[tid]);
        float z = sigm(spre[H + tid]);
        float n = tanhf(sxn[tid] + r * shn[tid]);
        float h = (1.f - z) * n + z * sh[tid];
        sh[tid] = h;
        hsum += h;
        if (t == CC - 1) g_xlb[tid] = hsum * (1.0f / CC);
      }
      __syncthreads();
    }
    grid.sync();
  }

  // ---- epilogue (layer-159 block only) ----
  if (is_layer && l == NLAYERS - 1){
    if (tid < H) sxc[tid] = fmaxf(hsum * (1.0f / NCH), 0.f);
    __syncthreads();
    if (tid < H){
      float xl   = g_xlb[tid];
      float xnew = xl * sxc[tid];
      float xbn  = (xnew - bn_mean[tid]) * rsqrtf(bn_var[tid] + 1e-5f)
                   * bn_gamma[tid] + bn_beta[tid];
      sx[tid] = fmaxf(xbn, 0.f);     // xr
    }
    __syncthreads();
    if (tid < NCLS + CC){
      const float* wrow; float acc;
      if (tid < NCLS){ wrow = fc_w + (size_t)tid * H; acc = fc_b[tid]; }
      else           { wrow = reg_w + (size_t)(tid - NCLS) * H; acc = reg_b[tid - NCLS]; }
#pragma unroll
      for (int q = 0; q < 40; q++){
        float4 wv = *(const float4*)(wrow + 4*q);
        float4 xv = *(const float4*)(sx + 4*q);
        acc = fmaf(wv.x, xv.x, acc);
        acc = fmaf(wv.y, xv.y, acc);
        acc = fmaf(wv.z, xv.z, acc);
        acc = fmaf(wv.w, xv.w, acc);
      }
      out[tid] = acc;     // f32 output — reference returns float32
    }
  }
}

extern "C" void kernel_launch(void* const* d_in, const int* in_sizes, int n_in,
                              void* d_out, int out_size, void* d_ws, size_t ws_size,
                              hipStream_t stream) {
  (void)in_sizes; (void)n_in; (void)out_size; (void)d_ws; (void)ws_size;

  const float* a0  = (const float*)d_in[0];
  const float* a1  = (const float*)d_in[1];
  const float* a2  = (const float*)d_in[2];
  const float* a3  = (const float*)d_in[3];
  const float* a4  = (const float*)d_in[4];
  const float* a5  = (const float*)d_in[5];
  const float* a6  = (const float*)d_in[6];
  const float* a7  = (const float*)d_in[7];
  const float* a8  = (const float*)d_in[8];
  const float* a9  = (const float*)d_in[9];
  const float* a10 = (const float*)d_in[10];
  const float* a11 = (const float*)d_in[11];
  const float* a12 = (const float*)d_in[12];
  const float* a13 = (const float*)d_in[13];
  const float* a14 = (const float*)d_in[14];
  const float* a15 = (const float*)d_in[15];
  const float* a16 = (const float*)d_in[16];
  const float* a17 = (const float*)d_in[17];
  const float* a18 = (const float*)d_in[18];
  const float* a19 = (const float*)d_in[19];
  const float* a20 = (const float*)d_in[20];
  float* po = (float*)d_out;

  void* args[] = {
    (void*)&a0,  (void*)&a1,  (void*)&a2,  (void*)&a3,  (void*)&a4,
    (void*)&a5,  (void*)&a6,  (void*)&a7,  (void*)&a8,  (void*)&a9,
    (void*)&a10, (void*)&a11, (void*)&a12, (void*)&a13, (void*)&a14,
    (void*)&a15, (void*)&a16, (void*)&a17, (void*)&a18, (void*)&a19,
    (void*)&a20, (void*)&po
  };

  hipLaunchCooperativeKernel((const void*)spectral_coop,
                             dim3(NLAYERS + NCH + 1), dim3(512),
                             args, 0, stream);
}

// Round 9
// 3902.373 us; speedup vs baseline: 1.4589x; 1.4589x over previous
//
#include <hip/hip_runtime.h>
#include <stdint.h>

#define H      160
#define G3     480
#define NCH    10
#define TCH    20
#define CC     200
#define NCLS   16
#define NLAYERS 160
#define NLEVELS 161
#define NFLAGS (NLEVELS * NCH + 1)   // level-t flags + xl flag

typedef unsigned int u32;

// static device scratch — no d_ws dependence; flags re-zeroed by zero_flags each call
__device__ float g_seq[NLEVELS * NCH * H];   // [161][10][160]
__device__ float g_xlb[H];
__device__ int   g_flg[NFLAGS];

__device__ __forceinline__ float sigm(float x){ return 1.0f / (1.0f + expf(-x)); }

__device__ __forceinline__ void st_rel(int* p, int v){
  __hip_atomic_store(p, v, __ATOMIC_RELEASE, __HIP_MEMORY_SCOPE_AGENT);
}
__device__ __forceinline__ int ld_acq(int* p){
  return __hip_atomic_load(p, __ATOMIC_ACQUIRE, __HIP_MEMORY_SCOPE_AGENT);
}
__device__ __forceinline__ void stf(float* p, float v){
  __hip_atomic_store(p, v, __ATOMIC_RELAXED, __HIP_MEMORY_SCOPE_AGENT);
}
__device__ __forceinline__ float ldf(float* p){
  return __hip_atomic_load(p, __ATOMIC_RELAXED, __HIP_MEMORY_SCOPE_AGENT);
}

__device__ __forceinline__ float dot160(const float4* __restrict__ w, const float* v){
  float a0 = 0.f, a1 = 0.f;
#pragma unroll
  for (int q = 0; q < 40; q += 2){
    float4 wa = w[q], wb = w[q+1];
    float4 va = *(const float4*)(v + 4*q);
    float4 vb = *(const float4*)(v + 4*q + 4);
    a0 = fmaf(wa.x, va.x, a0); a0 = fmaf(wa.y, va.y, a0);
    a0 = fmaf(wa.z, va.z, a0); a0 = fmaf(wa.w, va.w, a0);
    a1 = fmaf(wb.x, vb.x, a1); a1 = fmaf(wb.y, vb.y, a1);
    a1 = fmaf(wb.z, vb.z, a1); a1 = fmaf(wb.w, vb.w, a1);
  }
  return a0 + a1;
}

extern "C" __global__ void zero_flags_kernel(){
  int i = threadIdx.x + blockIdx.x * blockDim.x;
  if (i < NFLAGS) g_flg[i] = 0;
}

extern "C" __global__ __launch_bounds__(512, 2)
void spectral_wave(
  const float* __restrict__ x,
  const float* __restrict__ b_wih, const float* __restrict__ b_whh,
  const float* __restrict__ b_bih, const float* __restrict__ b_bhh,
  const float* __restrict__ g_wih, const float* __restrict__ g_whh,
  const float* __restrict__ g_bih, const float* __restrict__ g_bhh,
  const float* __restrict__ g3_wih, const float* __restrict__ g3_whh,
  const float* __restrict__ g3_bih, const float* __restrict__ g3_bhh,
  const float* __restrict__ bn_gamma, const float* __restrict__ bn_beta,
  const float* __restrict__ bn_mean,  const float* __restrict__ bn_var,
  const float* __restrict__ fc_w, const float* __restrict__ fc_b,
  const float* __restrict__ reg_w, const float* __restrict__ reg_b,
  float* __restrict__ out)
{
  const int tid = threadIdx.x;
  const int bid = blockIdx.x;
  int* flg = g_flg;

  __shared__ __align__(16) float sx[H];
  __shared__ __align__(16) float sh[H];
  __shared__ float spre[2*H];
  __shared__ float sxn[H];
  __shared__ float shn[H];
  __shared__ float sxc[H];

  if (bid < NLAYERS) {
    // ---------------- g3 layer block: layer l ----------------
    const int l = bid;
    const float4* wih_row = (const float4*)(g3_wih + ((size_t)l*G3 + tid)*H);
    const float4* whh_row = (const float4*)(g3_whh + ((size_t)l*G3 + tid)*H);
    float4 whhr[40];
    float bihj = 0.f, bhhj = 0.f;
    if (tid < G3){
#pragma unroll
      for (int q = 0; q < 40; q++) whhr[q] = whh_row[q];
      bihj = g3_bih[l*G3 + tid];
      bhhj = g3_bhh[l*G3 + tid];
    }
    if (tid < H) sh[tid] = 0.f;

    // prefetch W_ih into L1/L2 ahead of the wavefront (first-touch HBM off the critical path)
    float pf = 0.f;
    if (tid < G3){
#pragma unroll
      for (int q = 0; q < 40; q++) pf += wih_row[q].x;
    }
    if (pf == 1.0e30f) sxc[0] = pf;   // never true; defeats DCE
    __syncthreads();

    float hsum = 0.f;
    float* seq_in  = g_seq + (size_t)l * NCH * H;
    float* seq_out = g_seq + (size_t)(l+1) * NCH * H;
    int* f_in  = flg + l * NCH;
    int* f_out = flg + (l+1) * NCH;

    for (int t = 0; t < NCH; t++){
      // recurrent dot precomputed while waiting for the input flag
      float ahv = 0.f;
      if (tid < G3) ahv = bhhj + dot160(whhr, sh);
      if (tid == 0){
        while (ld_acq(&f_in[t]) == 0) {}
      }
      __syncthreads();
      if (tid < H) sx[tid] = ldf(&seq_in[t*H + tid]);
      __syncthreads();
      if (tid < G3){
        float ax = bihj + dot160(wih_row, sx);
        if (tid < 2*H) spre[tid] = ax + ahv;
        else { sxn[tid - 2*H] = ax; shn[tid - 2*H] = ahv; }
      }
      __syncthreads();
      if (tid < H){
        float r = sigm(spre[tid]);
        float z = sigm(spre[H + tid]);
        float n = tanhf(sxn[tid] + r * shn[tid]);
        float h = (1.f - z) * n + z * sh[tid];
        sh[tid] = h;
        hsum += h;
        stf(&seq_out[t*H + tid], h);
      }
      __syncthreads();                   // drains the seq_out stores (vmcnt 0) before release
      if (tid == 0) st_rel(&f_out[t], 1);
    }

    if (l == NLAYERS - 1){
      // epilogue: x_cat_l, wait x_l, BN+ReLU, heads
      if (tid < H) sxc[tid] = fmaxf(hsum * (1.0f / NCH), 0.f);
      if (tid == 0){
        while (ld_acq(&flg[NLEVELS*NCH]) == 0) {}
      }
      __syncthreads();
      if (tid < H){
        float xl   = ldf(&g_xlb[tid]);
        float xnew = xl * sxc[tid];
        float xbn  = (xnew - bn_mean[tid]) * rsqrtf(bn_var[tid] + 1e-5f)
                     * bn_gamma[tid] + bn_beta[tid];
        sx[tid] = fmaxf(xbn, 0.f);       // xr
      }
      __syncthreads();
      if (tid < NCLS + CC){
        const float* wrow; float acc;
        if (tid < NCLS){ wrow = fc_w + (size_t)tid * H; acc = fc_b[tid]; }
        else           { wrow = reg_w + (size_t)(tid - NCLS) * H; acc = reg_b[tid - NCLS]; }
#pragma unroll
        for (int q = 0; q < 40; q++){
          float4 wv = *(const float4*)(wrow + 4*q);
          float4 xv = *(const float4*)(sx + 4*q);
          acc = fmaf(wv.x, xv.x, acc);
          acc = fmaf(wv.y, xv.y, acc);
          acc = fmaf(wv.z, xv.z, acc);
          acc = fmaf(wv.w, xv.w, acc);
        }
        out[tid] = acc;                  // f32 output
      }
    }
  } else if (bid < NLAYERS + NCH) {
    // ---------------- branch GRU block b ----------------
    const int b = bid - NLAYERS;
    const float4* whh_row = (const float4*)(b_whh + ((size_t)b*G3 + tid)*H);
    float4 whhr[40];
    float wij = 0.f, bihj = 0.f, bhhj = 0.f;
    if (tid < G3){
#pragma unroll
      for (int q = 0; q < 40; q++) whhr[q] = whh_row[q];
      wij  = b_wih[b*G3 + tid];
      bihj = b_bih[b*G3 + tid];
      bhhj = b_bhh[b*G3 + tid];
    }
    if (tid < H) sh[tid] = 0.f;
    __syncthreads();
    for (int t = 0; t < TCH; t++){
      float xv = x[b*TCH + t];
      if (tid < G3){
        float ax = fmaf(xv, wij, bihj);
        float ah = bhhj + dot160(whhr, sh);
        if (tid < 2*H) spre[tid] = ax + ah;
        else { sxn[tid - 2*H] = ax; shn[tid - 2*H] = ah; }
      }
      __syncthreads();
      if (tid < H){
        float r = sigm(spre[tid]);
        float z = sigm(spre[H + tid]);
        float n = tanhf(sxn[tid] + r * shn[tid]);
        float h = (1.f - z) * n + z * sh[tid];
        sh[tid] = h;
        if (t == TCH - 1) stf(&g_seq[(size_t)b*H + tid], h);   // level 0, chunk b
      }
      __syncthreads();
    }
    if (tid == 0) st_rel(&flg[b], 1);
  } else {
    // ---------------- full-x GRU (200 steps) ----------------
    const float4* whh_row = (const float4*)(g_whh + (size_t)tid * H);
    float4 whhr[40];
    float wij = 0.f, bihj = 0.f, bhhj = 0.f;
    if (tid < G3){
#pragma unroll
      for (int q = 0; q < 40; q++) whhr[q] = whh_row[q];
      wij  = g_wih[tid];
      bihj = g_bih[tid];
      bhhj = g_bhh[tid];
    }
    if (tid < H) sh[tid] = 0.f;
    __syncthreads();
    float hsum = 0.f;
    for (int t = 0; t < CC; t++){
      float xv = x[t];
      if (tid < G3){
        float ax = fmaf(xv, wij, bihj);
        float ah = bhhj + dot160(whhr, sh);
        if (tid < 2*H) spre[tid] = ax + ah;
        else { sxn[tid - 2*H] = ax; shn[tid - 2*H] = ah; }
      }
      __syncthreads();
      if (tid < H){
        float r = sigm(spre[tid]);
        float z = sigm(spre[H + tid]);
        float n = tanhf(sxn[tid] + r * shn[tid]);
        float h = (1.f - z) * n + z * sh[tid];
        sh[tid] = h;
        hsum += h;
      }
      __syncthreads();
    }
    if (tid < H) stf(&g_xlb[tid], hsum * (1.0f / CC));
    __syncthreads();
    if (tid == 0) st_rel(&flg[NLEVELS*NCH], 1);
  }
}

extern "C" void kernel_launch(void* const* d_in, const int* in_sizes, int n_in,
                              void* d_out, int out_size, void* d_ws, size_t ws_size,
                              hipStream_t stream) {
  (void)in_sizes; (void)n_in; (void)out_size; (void)d_ws; (void)ws_size;

  hipLaunchKernelGGL(zero_flags_kernel, dim3((NFLAGS + 255)/256), dim3(256), 0, stream);

  dim3 grid(NLAYERS + NCH + 1);
  dim3 block(512);
  hipLaunchKernelGGL(spectral_wave, grid, block, 0, stream,
    (const float*)d_in[0],
    (const float*)d_in[1],  (const float*)d_in[2],
    (const float*)d_in[3],  (const float*)d_in[4],
    (const float*)d_in[5],  (const float*)d_in[6],
    (const float*)d_in[7],  (const float*)d_in[8],
    (const float*)d_in[9],  (const float*)d_in[10],
    (const float*)d_in[11], (const float*)d_in[12],
    (const float*)d_in[13], (const float*)d_in[14],
    (const float*)d_in[15], (const float*)d_in[16],
    (const float*)d_in[17], (const float*)d_in[18],
    (const float*)d_in[19], (const float*)d_in[20],
    (float*)d_out);
}